// Round 3
// baseline (372.910 us; speedup 1.0000x reference)
//
#include <hip/hip_runtime.h>
#include <math.h>

typedef unsigned short u16;
typedef unsigned int   u32;
typedef float f32x4  __attribute__((ext_vector_type(4)));
typedef float f32x16 __attribute__((ext_vector_type(16)));
typedef __bf16 bf16x8 __attribute__((ext_vector_type(8)));
typedef __bf16 bf16x2 __attribute__((ext_vector_type(2)));

#define SEQ   2048
#define BATCH 4
#define NH    16
#define DK    64
#define DM    1024
#define MTOT  (SEQ*BATCH)   /* 8192 rows */
#define SCL_QK 0.18033688011116016f   /* log2(e)/sqrt(64), folded into Q proj */

#if __has_builtin(__builtin_amdgcn_exp2f)
#define EXP2(x) __builtin_amdgcn_exp2f(x)   /* bare v_exp_f32; scores bounded by construction */
#else
#define EXP2(x) exp2f(x)
#endif

// counted-vmcnt barrier pair: loads stay in flight across the barrier (T4).
#define WAITCNT_VM(N) asm volatile("s_waitcnt vmcnt(" #N ")" ::: "memory")
#define BARRIER_FENCED() do {                                  \
    __builtin_amdgcn_s_barrier();                              \
    asm volatile("" ::: "memory");                             \
  } while (0)

static __device__ __forceinline__ u16 f2bf(float f) {
  __bf16 h = (__bf16)f;
  return __builtin_bit_cast(u16, h);
}
static __device__ __forceinline__ u32 pk2(float a, float b) {
  bf16x2 t = {(__bf16)a, (__bf16)b};          // -> v_cvt_pk_bf16_f32
  return __builtin_bit_cast(u32, t);
}

typedef __attribute__((address_space(1))) const void g1_t;
typedef __attribute__((address_space(3))) void l3_t;
static __device__ __forceinline__ void gload16(const void* g, void* l) {
  __builtin_amdgcn_global_load_lds((g1_t*)g, (l3_t*)l, 16, 0, 0);
}

static __device__ __forceinline__ void cast8(const float* __restrict__ src,
                                             u16* __restrict__ dst, int i) {
  float4 a = ((const float4*)src)[2 * i];
  float4 b = ((const float4*)src)[2 * i + 1];
  uint4 r;
  r.x = pk2(a.x, a.y); r.y = pk2(a.z, a.w);
  r.z = pk2(b.x, b.y); r.w = pk2(b.z, b.w);
  ((uint4*)dst)[i] = r;
}

// single-tensor cast (split path)
__global__ __launch_bounds__(256)
void cast_bf16(const float* __restrict__ src, u16* __restrict__ dst, int n8) {
  int i = blockIdx.x * 256 + threadIdx.x;
  if (i < n8) cast8(src, dst, i);
}

// weights-only fused cast: Wq,Wk,Wv -> w3 [3*DM,DM]; Wo -> wo_c. 2048 blocks.
__global__ __launch_bounds__(256)
void cast_w(const float* __restrict__ Wq, const float* __restrict__ Wk,
            const float* __restrict__ Wv, const float* __restrict__ Wo,
            u16* __restrict__ w3, u16* __restrict__ wo_c) {
  int bid = blockIdx.x;
  int t = bid >> 9, idx = bid & 511;          // 512 blocks x 131072/256 groups
  const float* src = (t == 0) ? Wq : (t == 1) ? Wk : (t == 2) ? Wv : Wo;
  u16* dst = (t < 3) ? (w3 + (size_t)t * DM * DM) : wo_c;
  cast8(src, dst, idx * 256 + threadIdx.x);
}

// everything-cast: q,k,v (4096 blocks each) + 4 weights (512 each) = 14336 blocks.
__global__ __launch_bounds__(256)
void cast_all(const float* __restrict__ q, const float* __restrict__ k,
              const float* __restrict__ v,
              const float* __restrict__ Wq, const float* __restrict__ Wk,
              const float* __restrict__ Wv, const float* __restrict__ Wo,
              u16* __restrict__ in_c, u16* __restrict__ w3, u16* __restrict__ wo_c) {
  int bid = blockIdx.x;
  const float* src; u16* dst; int idx;
  if (bid < 12288) {
    int t = bid >> 12; idx = bid & 4095;
    src = (t == 0) ? q : (t == 1) ? k : v;
    dst = in_c + (size_t)t * MTOT * DM;
  } else {
    int wb = bid - 12288;
    int t = wb >> 9; idx = wb & 511;
    src = (t == 0) ? Wq : (t == 1) ? Wk : (t == 2) ? Wv : Wo;
    dst = (t < 3) ? (w3 + (size_t)t * DM * DM) : wo_c;
  }
  cast8(src, dst, idx * 256 + threadIdx.x);
}

// Unified projection GEMM — v3: 3-buffer depth-2 pipeline with counted vmcnt
// (raw s_barrier; never vmcnt(0) in the main loop) + XCD-chunked swizzle (T1).
// Buffer hazard proof: iter kt = {vmcnt(4); barrier; compute(b[kt%3]);
// stage(kt+2 -> b[(kt+2)%3])}. stage(kt+2) overwrites b[(kt-1)%3]; all
// compute(kt-1) reads precede iter-kt's barrier in program order. In-flight
// writes at compute(kt): stages kt+1, kt+2 -> bufs != kt%3.
// OGEMM=0: seg = seg_base + bx>>3 picks {Q,K,V}: A in [SEQ,BATCH,DM] order, W = w3 seg,
//          epilogue: seg0 -> o0 [b,h,s,dk] *SCL_QK; seg1 -> o1 [b,h,s,dk]; seg2 -> o2 [b,h,dk,s]
// OGEMM=1: A = ctx row-major [M,DM], W = w3(=wo_c), out f32 o3 [(s*B+b)*DM+n]
template<int OGEMM>
__global__ __launch_bounds__(256, 4)
void gemm_k(const u16* __restrict__ a0, const u16* __restrict__ a1,
            const u16* __restrict__ a2, const u16* __restrict__ w3,
            const float* __restrict__ b0, const float* __restrict__ b1,
            const float* __restrict__ b2,
            u16* __restrict__ o0, u16* __restrict__ o1, u16* __restrict__ o2,
            float* __restrict__ o3, int seg_base)
{
  constexpr int BM = 128, BN = 128, BK = 32;
  __shared__ u16 As[3][BM * BK];
  __shared__ u16 Bs[3][BN * BK];

  // T1 chunked XCD swizzle: nwg divisible by 8 (1536 / 512) -> bijective.
  const int nwg = gridDim.x * gridDim.y;
  const int bid = blockIdx.y * gridDim.x + blockIdx.x;
  const int swz = (bid & 7) * (nwg >> 3) + (bid >> 3);
  const int bx  = swz % gridDim.x;
  const int by  = swz / gridDim.x;

  const int seg = OGEMM ? 0 : (seg_base + (bx >> 3));
  const int n0  = OGEMM ? bx * BN : (bx & 7) * BN;
  const int m0  = by * BM;
  const u16* A = OGEMM ? a0 : (seg == 0 ? a0 : seg == 1 ? a1 : a2);
  const u16* W = OGEMM ? w3 : (w3 + (size_t)seg * DM * DM);
  const float* bias = OGEMM ? b0 : (seg == 0 ? b0 : seg == 1 ? b1 : b2);

  const int tid  = threadIdx.x;
  const int w    = tid >> 6;
  const int lane = tid & 63;
  const int quad = lane >> 4;
  const int l15  = lane & 15;
  const int wm = (w >> 1) * 64;
  const int wn = (w & 1) * 64;

  size_t aoff[2], woff[2];
  for (int p = 0; p < 2; p++) {
    int row = w * 32 + p * 16 + (lane >> 2);
    int gm = m0 + row;
    if (OGEMM) {
      aoff[p] = (size_t)gm * DM + (lane & 3) * 8;
    } else {
      int bb = gm >> 11, s = gm & (SEQ - 1);
      aoff[p] = (size_t)(s * BATCH + bb) * DM + (lane & 3) * 8;
    }
    woff[p] = (size_t)(n0 + row) * DM + (lane & 3) * 8;
  }

  f32x4 zero4 = {0.f, 0.f, 0.f, 0.f};
  f32x4 acc[4][4];
  for (int i = 0; i < 4; i++)
    for (int j = 0; j < 4; j++)
      acc[i][j] = zero4;

  auto stage = [&](int kt, int bufi) {
#pragma unroll
    for (int p = 0; p < 2; p++) {
      gload16(A + aoff[p] + kt * BK, &As[bufi][(w * 32 + p * 16) * BK]);
      gload16(W + woff[p] + kt * BK, &Bs[bufi][(w * 32 + p * 16) * BK]);
    }
  };
  auto compute = [&](int cur) {
    bf16x8 af[4], bfr[4];
#pragma unroll
    for (int i = 0; i < 4; i++)
      af[i] = *(const bf16x8*)&As[cur][(wm + i * 16 + l15) * BK + quad * 8];
#pragma unroll
    for (int j = 0; j < 4; j++)
      bfr[j] = *(const bf16x8*)&Bs[cur][(wn + j * 16 + l15) * BK + quad * 8];
#pragma unroll
    for (int i = 0; i < 4; i++)
#pragma unroll
      for (int j = 0; j < 4; j++)
        acc[i][j] = __builtin_amdgcn_mfma_f32_16x16x32_bf16(af[i], bfr[j], acc[i][j], 0, 0, 0);
  };

  constexpr int NKT = DM / BK;   // 32
  stage(0, 0);
  stage(1, 1);                   // 8 loads/wave in flight
  int cur = 0;
  for (int kt = 0; kt < NKT - 1; kt++) {
    WAITCNT_VM(4);               // tile kt complete; tile kt+1 stays in flight
    BARRIER_FENCED();
    compute(cur);
    if (kt + 2 < NKT) {
      int nb = cur + 2; if (nb >= 3) nb -= 3;
      stage(kt + 2, nb);
    }
    cur = (cur + 1 == 3) ? 0 : cur + 1;
  }
  WAITCNT_VM(0);                 // final tile: full drain (nothing left to hide)
  BARRIER_FENCED();
  compute(cur);

  // C/D layout: col(n) = lane&15, row(m) = quad*4 + reg
  for (int j = 0; j < 4; j++) {
    int gn = n0 + wn + j * 16 + l15;
    float bv = bias[gn];
    int h = gn >> 6, dk = gn & 63;
    for (int i = 0; i < 4; i++) {
      int gmb = m0 + wm + i * 16 + quad * 4;
      for (int r = 0; r < 4; r++) {
        int gm = gmb + r;
        float val = acc[i][j][r] + bv;
        int bb = gm >> 11, s = gm & (SEQ - 1);
        if (OGEMM) {
          o3[(size_t)(s * BATCH + bb) * DM + gn] = val;
        } else if (seg == 0) {
          o0[((size_t)(bb * NH + h) * SEQ + s) * DK + dk] = f2bf(val * SCL_QK);
        } else if (seg == 1) {
          o1[((size_t)(bb * NH + h) * SEQ + s) * DK + dk] = f2bf(val);
        } else {
          o2[((size_t)(bb * NH + h) * DK + dk) * SEQ + s] = f2bf(val);
        }
      }
    }
  }
}

// ---------------------------------------------------------------------------
// Flash attention v3: 32x32x16 MFMA, no P LDS round-trip (lane^32 exchange),
// 3-buffer depth-2 K/V pipeline with counted vmcnt (same proof as gemm_k).
// Q,K [bh,s,dk]; VT [bh,dk,s]; ctx [b*SEQ+s, DM] bf16.
// 256 threads = 4 waves x 32 q = 128 q/block. One-pass softmax (Q pre-scaled,
// exp2 domain).
//   A/B frag (32x32x16): row/col = lane&31, k = (lane>>5)*8 + elem
//   C/D: col = lane&31, row R(reg) = (reg&3) + 8*(reg>>2) + 4*(lane>>5)
__global__ __launch_bounds__(256, 4)
void attn3(const u16* __restrict__ Q, const u16* __restrict__ K,
           const u16* __restrict__ VT, u16* __restrict__ ctx)
{
  __shared__ u16 Ks[3][64 * 64];  // [buf][key][dk], 16B-group XOR swizzled
  __shared__ u16 Vs[3][64 * 64];  // [buf][dk][key], swizzled

  const int bh = blockIdx.x;
  const int qt = blockIdx.y;
  const int b  = bh >> 4, h = bh & 15;
  const int tid  = threadIdx.x;
  const int w    = tid >> 6;
  const int lane = tid & 63;
  const int l31  = lane & 31;
  const int hi   = lane >> 5;

  const u16* Qb = Q  + (size_t)bh * SEQ * DK;
  const u16* Kb = K  + (size_t)bh * SEQ * DK;
  const u16* Vb = VT + (size_t)bh * DK * SEQ;

  const int qbase = qt * 128 + w * 32;
  const int qrow  = qbase + l31;

  // Q row in registers: qf[ks] covers k = ks*16 + hi*8 .. +7
  bf16x8 qf[4];
#pragma unroll
  for (int ks = 0; ks < 4; ks++)
    qf[ks] = *(const bf16x8*)&Qb[(size_t)qrow * DK + ks * 16 + hi * 8];

  // staging: lane -> row r0 (8 rows/wave per gload), source col-group XOR-swizzled
  const int r0 = tid >> 3;                 // 0..31
  const int sw = (tid & 7) ^ (r0 & 7);

#define STAGE(kbb, bufi) do {                                                       \
    _Pragma("unroll")                                                               \
    for (int p = 0; p < 2; p++) {                                                   \
      int row = p * 32 + r0;                                                        \
      gload16(&Kb[(size_t)((kbb) * 64 + row) * DK + sw * 8],                        \
              &Ks[bufi][(p * 32 + w * 8) * 64]);                                    \
      gload16(&Vb[(size_t)row * SEQ + (kbb) * 64 + sw * 8],                         \
              &Vs[bufi][(p * 32 + w * 8) * 64]);                                    \
    }                                                                               \
  } while (0)

  f32x16 z16;
#pragma unroll
  for (int i = 0; i < 16; i++) z16[i] = 0.f;

  f32x16 ot0 = z16, ot1 = z16;             // O^T accumulators (dk blocks 0,1)
  float2 ls2 = {0.f, 0.f};

  u32 wp[8];

#define SOFTMAX_BLK(SA) do {                                                        \
    _Pragma("unroll")                                                               \
    for (int g = 0; g < 8; g++) {                                                   \
      float pa = EXP2(SA[2 * g]);                                                   \
      float pb = EXP2(SA[2 * g + 1]);                                               \
      ls2.x += pa; ls2.y += pb;                                                     \
      wp[g] = pk2(pa, pb);                                                          \
    }                                                                               \
  } while (0)

#define PVSTEP(VsB, KSB, KSL) do {                                                  \
    u32 a0 = wp[(KSB) * 4 + 0], a1 = wp[(KSB) * 4 + 1];                             \
    u32 a2 = wp[(KSB) * 4 + 2], a3 = wp[(KSB) * 4 + 3];                             \
    u32 s0 = hi ? a0 : a2, s1 = hi ? a1 : a3;                                       \
    u32 x0 = (u32)__shfl_xor((int)s0, 32);                                          \
    u32 x1 = (u32)__shfl_xor((int)s1, 32);                                          \
    uint4 pw;                                                                       \
    pw.x = hi ? x0 : a0; pw.y = hi ? x1 : a1;                                       \
    pw.z = hi ? a2 : x0; pw.w = hi ? a3 : x1;                                       \
    bf16x8 pf = __builtin_bit_cast(bf16x8, pw);                                     \
    const int gg = (((KSL) * 2 + hi) ^ (l31 & 7)) * 8;                              \
    bf16x8 vf0 = *(const bf16x8*)&VsB[l31 * 64 + gg];                               \
    bf16x8 vf1 = *(const bf16x8*)&VsB[(32 + l31) * 64 + gg];                        \
    ot0 = __builtin_amdgcn_mfma_f32_32x32x16_bf16(vf0, pf, ot0, 0, 0, 0);           \
    ot1 = __builtin_amdgcn_mfma_f32_32x32x16_bf16(vf1, pf, ot1, 0, 0, 0);           \
  } while (0)

#define BODY(curi) do {                                                             \
    const u16* KsB = &Ks[curi][0];                                                  \
    const u16* VsB = &Vs[curi][0];                                                  \
    f32x16 sa0 = z16, sa1 = z16;                                                    \
    _Pragma("unroll")                                                               \
    for (int ks = 0; ks < 4; ks++) {                                                \
      const int g0 = ((ks * 2 + hi) ^ (l31 & 7)) * 8;                               \
      bf16x8 kf0 = *(const bf16x8*)&KsB[l31 * 64 + g0];                             \
      bf16x8 kf1 = *(const bf16x8*)&KsB[(32 + l31) * 64 + g0];                      \
      sa0 = __builtin_amdgcn_mfma_f32_32x32x16_bf16(kf0, qf[ks], sa0, 0, 0, 0);     \
      sa1 = __builtin_amdgcn_mfma_f32_32x32x16_bf16(kf1, qf[ks], sa1, 0, 0, 0);     \
    }                                                                               \
    SOFTMAX_BLK(sa0);                                                               \
    PVSTEP(VsB, 0, 0);                                                              \
    PVSTEP(VsB, 1, 1);                                                              \
    SOFTMAX_BLK(sa1);                                                               \
    PVSTEP(VsB, 0, 2);                                                              \
    PVSTEP(VsB, 1, 3);                                                              \
  } while (0)

  constexpr int NKB = SEQ / 64;  // 32
  STAGE(0, 0);
  STAGE(1, 1);                   // 8 loads/wave in flight
  int cur = 0;
  for (int kb = 0; kb < NKB - 1; kb++) {
    WAITCNT_VM(4);               // tile kb complete; kb+1 stays in flight
    BARRIER_FENCED();
    BODY(cur);
    if (kb + 2 < NKB) {
      int nb = cur + 2; if (nb >= 3) nb -= 3;
      STAGE(kb + 2, nb);
    }
    cur = (cur + 1 == 3) ? 0 : cur + 1;
  }
  WAITCNT_VM(0);
  BARRIER_FENCED();
  BODY(cur);

  // ---- epilogue: finish denominator across the hi halves, scale, store
  float ls = ls2.x + ls2.y;
  ls += __shfl_xor(ls, 32);
  float inv = 1.0f / ls;

  u16* crow = ctx + ((size_t)(b * SEQ + qrow)) * DM + h * DK;

#define STORE_BLK(OT, DKB) do {                                                     \
    _Pragma("unroll")                                                               \
    for (int t = 0; t < 4; t++) {                                                   \
      uint2 pr;                                                                     \
      pr.x = pk2(OT[4 * t + 0] * inv, OT[4 * t + 1] * inv);                         \
      pr.y = pk2(OT[4 * t + 2] * inv, OT[4 * t + 3] * inv);                         \
      *(uint2*)&crow[(DKB) * 32 + t * 8 + hi * 4] = pr;                             \
    }                                                                               \
  } while (0)

  STORE_BLK(ot0, 0);
  STORE_BLK(ot1, 1);

#undef STAGE
#undef SOFTMAX_BLK
#undef PVSTEP
#undef BODY
#undef STORE_BLK
}

extern "C" void kernel_launch(void* const* d_in, const int* in_sizes, int n_in,
                              void* d_out, int out_size, void* d_ws, size_t ws_size,
                              hipStream_t stream)
{
  const float* q  = (const float*)d_in[0];
  const float* k  = (const float*)d_in[1];
  const float* v  = (const float*)d_in[2];
  const float* Wq = (const float*)d_in[3];
  const float* bq = (const float*)d_in[4];
  const float* Wk = (const float*)d_in[5];
  const float* bk = (const float*)d_in[6];
  const float* Wv = (const float*)d_in[7];
  const float* bv = (const float*)d_in[8];
  const float* Wo = (const float*)d_in[9];
  const float* bo = (const float*)d_in[10];

  const size_t SZ_IN  = (size_t)MTOT * DM;      // elements per [8192,1024] bf16 buffer
  const size_t SZ_W   = (size_t)DM * DM;
  const size_t NEED_FUSED = (3 * SZ_IN + 3 * SZ_W + SZ_W + 3 * SZ_IN) * 2;  // 104 MiB

  dim3 cblk(256);
  dim3 ggq(24, 64);
  dim3 ggs(8, 64);

  if (ws_size >= NEED_FUSED) {
    u16* in_c  = (u16*)d_ws;                    // q,k,v bf16: 3 x 16.78 MB
    u16* w3    = in_c + 3 * SZ_IN;              // [3*DM, DM]
    u16* wo_c  = w3   + 3 * SZ_W;
    u16* q_ws  = wo_c + SZ_W;                   // [b,h,s,dk] (pre-scaled)
    u16* k_ws  = q_ws + SZ_IN;
    u16* vt_ws = k_ws + SZ_IN;                  // [b,h,dk,s]
    u16* ctx   = in_c;                          // alias (inputs dead after QKV gemm)

    cast_all<<<14336, cblk, 0, stream>>>(q, k, v, Wq, Wk, Wv, Wo, in_c, w3, wo_c);
    gemm_k<0><<<ggq, cblk, 0, stream>>>(in_c, in_c + SZ_IN, in_c + 2 * SZ_IN, w3,
                                        bq, bk, bv, q_ws, k_ws, vt_ws, nullptr, 0);
    attn3<<<dim3(BATCH * NH, SEQ / 128), cblk, 0, stream>>>(q_ws, k_ws, vt_ws, ctx);
    gemm_k<1><<<ggs, cblk, 0, stream>>>(ctx, ctx, ctx, wo_c,
                                        bo, bo, bo, nullptr, nullptr, nullptr,
                                        (float*)d_out, 0);
  } else {
    u16* in_c  = (u16*)d_ws;                    // single 16.78 MB cast buffer
    u16* w3    = in_c + SZ_IN;
    u16* wo_c  = w3   + 3 * SZ_W;
    u16* q_ws  = wo_c + SZ_W;
    u16* k_ws  = q_ws + SZ_IN;
    u16* vt_ws = k_ws + SZ_IN;
    u16* ctx   = in_c;

    const int NA8 = MTOT * DM / 8;
    cast_w<<<2048, cblk, 0, stream>>>(Wq, Wk, Wv, Wo, w3, wo_c);
    cast_bf16<<<NA8 / 256, cblk, 0, stream>>>(q, in_c, NA8);
    gemm_k<0><<<ggs, cblk, 0, stream>>>(in_c, in_c, in_c, w3, bq, bk, bv,
                                        q_ws, k_ws, vt_ws, nullptr, 0);
    cast_bf16<<<NA8 / 256, cblk, 0, stream>>>(k, in_c, NA8);
    gemm_k<0><<<ggs, cblk, 0, stream>>>(in_c, in_c, in_c, w3, bq, bk, bv,
                                        q_ws, k_ws, vt_ws, nullptr, 1);
    cast_bf16<<<NA8 / 256, cblk, 0, stream>>>(v, in_c, NA8);
    gemm_k<0><<<ggs, cblk, 0, stream>>>(in_c, in_c, in_c, w3, bq, bk, bv,
                                        q_ws, k_ws, vt_ws, nullptr, 2);
    attn3<<<dim3(BATCH * NH, SEQ / 128), cblk, 0, stream>>>(q_ws, k_ws, vt_ws, ctx);
    gemm_k<1><<<ggs, cblk, 0, stream>>>(ctx, ctx, ctx, wo_c,
                                        bo, bo, bo, nullptr, nullptr, nullptr,
                                        (float*)d_out, 0);
  }
}

// Round 4
// 360.678 us; speedup vs baseline: 1.0339x; 1.0339x over previous
//
#include <hip/hip_runtime.h>
#include <math.h>

typedef unsigned short u16;
typedef unsigned int   u32;
typedef float f32x4  __attribute__((ext_vector_type(4)));
typedef float f32x16 __attribute__((ext_vector_type(16)));
typedef __bf16 bf16x8 __attribute__((ext_vector_type(8)));
typedef __bf16 bf16x2 __attribute__((ext_vector_type(2)));

#define SEQ   2048
#define BATCH 4
#define NH    16
#define DK    64
#define DM    1024
#define MTOT  (SEQ*BATCH)   /* 8192 rows */
#define SCL_QK 0.18033688011116016f   /* log2(e)/sqrt(64), folded into Q proj */

#if __has_builtin(__builtin_amdgcn_exp2f)
#define EXP2(x) __builtin_amdgcn_exp2f(x)   /* bare v_exp_f32; scores bounded by construction */
#else
#define EXP2(x) exp2f(x)
#endif

// counted-vmcnt barrier pair: loads stay in flight across the barrier (T4).
#define WAITCNT_VM(N) asm volatile("s_waitcnt vmcnt(" #N ")" ::: "memory")
#define BARRIER_FENCED() do {                                  \
    __builtin_amdgcn_s_barrier();                              \
    asm volatile("" ::: "memory");                             \
  } while (0)

static __device__ __forceinline__ u16 f2bf(float f) {
  __bf16 h = (__bf16)f;
  return __builtin_bit_cast(u16, h);
}
static __device__ __forceinline__ u32 pk2(float a, float b) {
  bf16x2 t = {(__bf16)a, (__bf16)b};          // -> v_cvt_pk_bf16_f32
  return __builtin_bit_cast(u32, t);
}

typedef __attribute__((address_space(1))) const void g1_t;
typedef __attribute__((address_space(3))) void l3_t;
static __device__ __forceinline__ void gload16(const void* g, void* l) {
  __builtin_amdgcn_global_load_lds((g1_t*)g, (l3_t*)l, 16, 0, 0);
}

static __device__ __forceinline__ void cast8(const float* __restrict__ src,
                                             u16* __restrict__ dst, int i) {
  float4 a = ((const float4*)src)[2 * i];
  float4 b = ((const float4*)src)[2 * i + 1];
  uint4 r;
  r.x = pk2(a.x, a.y); r.y = pk2(a.z, a.w);
  r.z = pk2(b.x, b.y); r.w = pk2(b.z, b.w);
  ((uint4*)dst)[i] = r;
}

// single-tensor cast (split path)
__global__ __launch_bounds__(256)
void cast_bf16(const float* __restrict__ src, u16* __restrict__ dst, int n8) {
  int i = blockIdx.x * 256 + threadIdx.x;
  if (i < n8) cast8(src, dst, i);
}

// weights-only fused cast: Wq,Wk,Wv -> w3 [3*DM,DM]; Wo -> wo_c. 2048 blocks.
__global__ __launch_bounds__(256)
void cast_w(const float* __restrict__ Wq, const float* __restrict__ Wk,
            const float* __restrict__ Wv, const float* __restrict__ Wo,
            u16* __restrict__ w3, u16* __restrict__ wo_c) {
  int bid = blockIdx.x;
  int t = bid >> 9, idx = bid & 511;          // 512 blocks x 131072/256 groups
  const float* src = (t == 0) ? Wq : (t == 1) ? Wk : (t == 2) ? Wv : Wo;
  u16* dst = (t < 3) ? (w3 + (size_t)t * DM * DM) : wo_c;
  cast8(src, dst, idx * 256 + threadIdx.x);
}

// everything-cast: q,k,v (4096 blocks each) + 4 weights (512 each) = 14336 blocks.
__global__ __launch_bounds__(256)
void cast_all(const float* __restrict__ q, const float* __restrict__ k,
              const float* __restrict__ v,
              const float* __restrict__ Wq, const float* __restrict__ Wk,
              const float* __restrict__ Wv, const float* __restrict__ Wo,
              u16* __restrict__ in_c, u16* __restrict__ w3, u16* __restrict__ wo_c) {
  int bid = blockIdx.x;
  const float* src; u16* dst; int idx;
  if (bid < 12288) {
    int t = bid >> 12; idx = bid & 4095;
    src = (t == 0) ? q : (t == 1) ? k : v;
    dst = in_c + (size_t)t * MTOT * DM;
  } else {
    int wb = bid - 12288;
    int t = wb >> 9; idx = wb & 511;
    src = (t == 0) ? Wq : (t == 1) ? Wk : (t == 2) ? Wv : Wo;
    dst = (t < 3) ? (w3 + (size_t)t * DM * DM) : wo_c;
  }
  cast8(src, dst, idx * 256 + threadIdx.x);
}

// Unified projection GEMM — v4: 2-buffer depth-1 pipeline with counted vmcnt
// (32 KB LDS keeps 4 blocks/CU; no vmcnt(0) in the main loop) + XCD swizzle.
// Iter kt: {stage(kt+1 -> cur^1); vmcnt(4); barrier; compute(cur); barrier}.
// - vmcnt(4) waits only for stage(kt) (issued one full iter earlier); the 4
//   stage(kt+1) loads stay in flight across both barriers.
// - Hazard: stage(kt+1) overwrites cur^1, last read by compute(kt-1) which
//   precedes iter kt-1's trailing barrier. Each wave's vmcnt(4) precedes the
//   pre-compute barrier, so post-barrier reads see all waves' staged data.
// OGEMM=0: seg = seg_base + bx>>3 picks {Q,K,V}: A in [SEQ,BATCH,DM] order, W = w3 seg,
//          epilogue: seg0 -> o0 [b,h,s,dk] *SCL_QK; seg1 -> o1 [b,h,s,dk]; seg2 -> o2 [b,h,dk,s]
// OGEMM=1: A = ctx row-major [M,DM], W = w3(=wo_c), out f32 o3 [(s*B+b)*DM+n]
template<int OGEMM>
__global__ __launch_bounds__(256, 4)
void gemm_k(const u16* __restrict__ a0, const u16* __restrict__ a1,
            const u16* __restrict__ a2, const u16* __restrict__ w3,
            const float* __restrict__ b0, const float* __restrict__ b1,
            const float* __restrict__ b2,
            u16* __restrict__ o0, u16* __restrict__ o1, u16* __restrict__ o2,
            float* __restrict__ o3, int seg_base)
{
  constexpr int BM = 128, BN = 128, BK = 32;
  __shared__ u16 As[2][BM * BK];
  __shared__ u16 Bs[2][BN * BK];

  // T1 chunked XCD swizzle: nwg divisible by 8 (1536 / 512) -> bijective.
  const int nwg = gridDim.x * gridDim.y;
  const int bid = blockIdx.y * gridDim.x + blockIdx.x;
  const int swz = (bid & 7) * (nwg >> 3) + (bid >> 3);
  const int bx  = swz % gridDim.x;
  const int by  = swz / gridDim.x;

  const int seg = OGEMM ? 0 : (seg_base + (bx >> 3));
  const int n0  = OGEMM ? bx * BN : (bx & 7) * BN;
  const int m0  = by * BM;
  const u16* A = OGEMM ? a0 : (seg == 0 ? a0 : seg == 1 ? a1 : a2);
  const u16* W = OGEMM ? w3 : (w3 + (size_t)seg * DM * DM);
  const float* bias = OGEMM ? b0 : (seg == 0 ? b0 : seg == 1 ? b1 : b2);

  const int tid  = threadIdx.x;
  const int w    = tid >> 6;
  const int lane = tid & 63;
  const int quad = lane >> 4;
  const int l15  = lane & 15;
  const int wm = (w >> 1) * 64;
  const int wn = (w & 1) * 64;

  size_t aoff[2], woff[2];
  for (int p = 0; p < 2; p++) {
    int row = w * 32 + p * 16 + (lane >> 2);
    int gm = m0 + row;
    if (OGEMM) {
      aoff[p] = (size_t)gm * DM + (lane & 3) * 8;
    } else {
      int bb = gm >> 11, s = gm & (SEQ - 1);
      aoff[p] = (size_t)(s * BATCH + bb) * DM + (lane & 3) * 8;
    }
    woff[p] = (size_t)(n0 + row) * DM + (lane & 3) * 8;
  }

  f32x4 zero4 = {0.f, 0.f, 0.f, 0.f};
  f32x4 acc[4][4];
  for (int i = 0; i < 4; i++)
    for (int j = 0; j < 4; j++)
      acc[i][j] = zero4;

  auto stage = [&](int kt, int bufi) {
#pragma unroll
    for (int p = 0; p < 2; p++) {
      gload16(A + aoff[p] + kt * BK, &As[bufi][(w * 32 + p * 16) * BK]);
      gload16(W + woff[p] + kt * BK, &Bs[bufi][(w * 32 + p * 16) * BK]);
    }
  };
  auto compute = [&](int cur) {
    bf16x8 af[4], bfr[4];
#pragma unroll
    for (int i = 0; i < 4; i++)
      af[i] = *(const bf16x8*)&As[cur][(wm + i * 16 + l15) * BK + quad * 8];
#pragma unroll
    for (int j = 0; j < 4; j++)
      bfr[j] = *(const bf16x8*)&Bs[cur][(wn + j * 16 + l15) * BK + quad * 8];
#pragma unroll
    for (int i = 0; i < 4; i++)
#pragma unroll
      for (int j = 0; j < 4; j++)
        acc[i][j] = __builtin_amdgcn_mfma_f32_16x16x32_bf16(af[i], bfr[j], acc[i][j], 0, 0, 0);
  };

  constexpr int NKT = DM / BK;   // 32
  stage(0, 0);
  int cur = 0;
  for (int kt = 0; kt < NKT - 1; kt++) {
    stage(kt + 1, cur ^ 1);      // issue next tile first
    WAITCNT_VM(4);               // tile kt retired; kt+1's 4 loads stay in flight
    BARRIER_FENCED();
    compute(cur);
    BARRIER_FENCED();            // readers done before next iter's stage overwrite
    cur ^= 1;
  }
  WAITCNT_VM(0);                 // final tile: full drain (nothing left to hide)
  BARRIER_FENCED();
  compute(cur);

  // C/D layout: col(n) = lane&15, row(m) = quad*4 + reg
  for (int j = 0; j < 4; j++) {
    int gn = n0 + wn + j * 16 + l15;
    float bv = bias[gn];
    int h = gn >> 6, dk = gn & 63;
    for (int i = 0; i < 4; i++) {
      int gmb = m0 + wm + i * 16 + quad * 4;
      for (int r = 0; r < 4; r++) {
        int gm = gmb + r;
        float val = acc[i][j][r] + bv;
        int bb = gm >> 11, s = gm & (SEQ - 1);
        if (OGEMM) {
          o3[(size_t)(s * BATCH + bb) * DM + gn] = val;
        } else if (seg == 0) {
          o0[((size_t)(bb * NH + h) * SEQ + s) * DK + dk] = f2bf(val * SCL_QK);
        } else if (seg == 1) {
          o1[((size_t)(bb * NH + h) * SEQ + s) * DK + dk] = f2bf(val);
        } else {
          o2[((size_t)(bb * NH + h) * DK + dk) * SEQ + s] = f2bf(val);
        }
      }
    }
  }
}

// ---------------------------------------------------------------------------
// Flash attention v4: 32x32x16 MFMA, no P LDS round-trip (lane^32 exchange),
// 2-buffer depth-1 K/V pipeline with counted vmcnt (same schedule/proof as
// gemm_k v4; 32 KB LDS keeps 4 blocks/CU).
// Q,K [bh,s,dk]; VT [bh,dk,s]; ctx [b*SEQ+s, DM] bf16.
// 256 threads = 4 waves x 32 q = 128 q/block. One-pass softmax (Q pre-scaled,
// exp2 domain).
//   A/B frag (32x32x16): row/col = lane&31, k = (lane>>5)*8 + elem
//   C/D: col = lane&31, row R(reg) = (reg&3) + 8*(reg>>2) + 4*(lane>>5)
__global__ __launch_bounds__(256, 4)
void attn3(const u16* __restrict__ Q, const u16* __restrict__ K,
           const u16* __restrict__ VT, u16* __restrict__ ctx)
{
  __shared__ u16 Ks[2][64 * 64];  // [buf][key][dk], 16B-group XOR swizzled
  __shared__ u16 Vs[2][64 * 64];  // [buf][dk][key], swizzled

  const int bh = blockIdx.x;
  const int qt = blockIdx.y;
  const int b  = bh >> 4, h = bh & 15;
  const int tid  = threadIdx.x;
  const int w    = tid >> 6;
  const int lane = tid & 63;
  const int l31  = lane & 31;
  const int hi   = lane >> 5;

  const u16* Qb = Q  + (size_t)bh * SEQ * DK;
  const u16* Kb = K  + (size_t)bh * SEQ * DK;
  const u16* Vb = VT + (size_t)bh * DK * SEQ;

  const int qbase = qt * 128 + w * 32;
  const int qrow  = qbase + l31;

  // Q row in registers: qf[ks] covers k = ks*16 + hi*8 .. +7
  bf16x8 qf[4];
#pragma unroll
  for (int ks = 0; ks < 4; ks++)
    qf[ks] = *(const bf16x8*)&Qb[(size_t)qrow * DK + ks * 16 + hi * 8];

  // staging: lane -> row r0 (8 rows/wave per gload), source col-group XOR-swizzled
  const int r0 = tid >> 3;                 // 0..31
  const int sw = (tid & 7) ^ (r0 & 7);

#define STAGE(kbb, bufi) do {                                                       \
    _Pragma("unroll")                                                               \
    for (int p = 0; p < 2; p++) {                                                   \
      int row = p * 32 + r0;                                                        \
      gload16(&Kb[(size_t)((kbb) * 64 + row) * DK + sw * 8],                        \
              &Ks[bufi][(p * 32 + w * 8) * 64]);                                    \
      gload16(&Vb[(size_t)row * SEQ + (kbb) * 64 + sw * 8],                         \
              &Vs[bufi][(p * 32 + w * 8) * 64]);                                    \
    }                                                                               \
  } while (0)

  f32x16 z16;
#pragma unroll
  for (int i = 0; i < 16; i++) z16[i] = 0.f;

  f32x16 ot0 = z16, ot1 = z16;             // O^T accumulators (dk blocks 0,1)
  float2 ls2 = {0.f, 0.f};

  u32 wp[8];

#define SOFTMAX_BLK(SA) do {                                                        \
    _Pragma("unroll")                                                               \
    for (int g = 0; g < 8; g++) {                                                   \
      float pa = EXP2(SA[2 * g]);                                                   \
      float pb = EXP2(SA[2 * g + 1]);                                               \
      ls2.x += pa; ls2.y += pb;                                                     \
      wp[g] = pk2(pa, pb);                                                          \
    }                                                                               \
  } while (0)

#define PVSTEP(VsB, KSB, KSL) do {                                                  \
    u32 a0 = wp[(KSB) * 4 + 0], a1 = wp[(KSB) * 4 + 1];                             \
    u32 a2 = wp[(KSB) * 4 + 2], a3 = wp[(KSB) * 4 + 3];                             \
    u32 s0 = hi ? a0 : a2, s1 = hi ? a1 : a3;                                       \
    u32 x0 = (u32)__shfl_xor((int)s0, 32);                                          \
    u32 x1 = (u32)__shfl_xor((int)s1, 32);                                          \
    uint4 pw;                                                                       \
    pw.x = hi ? x0 : a0; pw.y = hi ? x1 : a1;                                       \
    pw.z = hi ? a2 : x0; pw.w = hi ? a3 : x1;                                       \
    bf16x8 pf = __builtin_bit_cast(bf16x8, pw);                                     \
    const int gg = (((KSL) * 2 + hi) ^ (l31 & 7)) * 8;                              \
    bf16x8 vf0 = *(const bf16x8*)&VsB[l31 * 64 + gg];                               \
    bf16x8 vf1 = *(const bf16x8*)&VsB[(32 + l31) * 64 + gg];                        \
    ot0 = __builtin_amdgcn_mfma_f32_32x32x16_bf16(vf0, pf, ot0, 0, 0, 0);           \
    ot1 = __builtin_amdgcn_mfma_f32_32x32x16_bf16(vf1, pf, ot1, 0, 0, 0);           \
  } while (0)

#define BODY(curi) do {                                                             \
    const u16* KsB = &Ks[curi][0];                                                  \
    const u16* VsB = &Vs[curi][0];                                                  \
    f32x16 sa0 = z16, sa1 = z16;                                                    \
    _Pragma("unroll")                                                               \
    for (int ks = 0; ks < 4; ks++) {                                                \
      const int g0 = ((ks * 2 + hi) ^ (l31 & 7)) * 8;                               \
      bf16x8 kf0 = *(const bf16x8*)&KsB[l31 * 64 + g0];                             \
      bf16x8 kf1 = *(const bf16x8*)&KsB[(32 + l31) * 64 + g0];                      \
      sa0 = __builtin_amdgcn_mfma_f32_32x32x16_bf16(kf0, qf[ks], sa0, 0, 0, 0);     \
      sa1 = __builtin_amdgcn_mfma_f32_32x32x16_bf16(kf1, qf[ks], sa1, 0, 0, 0);     \
    }                                                                               \
    SOFTMAX_BLK(sa0);                                                               \
    PVSTEP(VsB, 0, 0);                                                              \
    PVSTEP(VsB, 1, 1);                                                              \
    SOFTMAX_BLK(sa1);                                                               \
    PVSTEP(VsB, 0, 2);                                                              \
    PVSTEP(VsB, 1, 3);                                                              \
  } while (0)

  constexpr int NKB = SEQ / 64;  // 32
  STAGE(0, 0);
  for (int kb = 0; kb < NKB - 1; kb++) {
    const int cur = kb & 1;
    STAGE(kb + 1, cur ^ 1);      // issue next tile first
    WAITCNT_VM(4);               // tile kb retired; kb+1's 4 loads in flight
    BARRIER_FENCED();
    BODY(cur);
    BARRIER_FENCED();            // readers done before next iter's stage overwrite
  }
  WAITCNT_VM(0);
  BARRIER_FENCED();
  BODY((NKB - 1) & 1);

  // ---- epilogue: finish denominator across the hi halves, scale, store
  float ls = ls2.x + ls2.y;
  ls += __shfl_xor(ls, 32);
  float inv = 1.0f / ls;

  u16* crow = ctx + ((size_t)(b * SEQ + qrow)) * DM + h * DK;

#define STORE_BLK(OT, DKB) do {                                                     \
    _Pragma("unroll")                                                               \
    for (int t = 0; t < 4; t++) {                                                   \
      uint2 pr;                                                                     \
      pr.x = pk2(OT[4 * t + 0] * inv, OT[4 * t + 1] * inv);                         \
      pr.y = pk2(OT[4 * t + 2] * inv, OT[4 * t + 3] * inv);                         \
      *(uint2*)&crow[(DKB) * 32 + t * 8 + hi * 4] = pr;                             \
    }                                                                               \
  } while (0)

  STORE_BLK(ot0, 0);
  STORE_BLK(ot1, 1);

#undef STAGE
#undef SOFTMAX_BLK
#undef PVSTEP
#undef BODY
#undef STORE_BLK
}

extern "C" void kernel_launch(void* const* d_in, const int* in_sizes, int n_in,
                              void* d_out, int out_size, void* d_ws, size_t ws_size,
                              hipStream_t stream)
{
  const float* q  = (const float*)d_in[0];
  const float* k  = (const float*)d_in[1];
  const float* v  = (const float*)d_in[2];
  const float* Wq = (const float*)d_in[3];
  const float* bq = (const float*)d_in[4];
  const float* Wk = (const float*)d_in[5];
  const float* bk = (const float*)d_in[6];
  const float* Wv = (const float*)d_in[7];
  const float* bv = (const float*)d_in[8];
  const float* Wo = (const float*)d_in[9];
  const float* bo = (const float*)d_in[10];

  const size_t SZ_IN  = (size_t)MTOT * DM;      // elements per [8192,1024] bf16 buffer
  const size_t SZ_W   = (size_t)DM * DM;
  const size_t NEED_FUSED = (3 * SZ_IN + 3 * SZ_W + SZ_W + 3 * SZ_IN) * 2;  // 104 MiB

  dim3 cblk(256);
  dim3 ggq(24, 64);
  dim3 ggs(8, 64);

  if (ws_size >= NEED_FUSED) {
    u16* in_c  = (u16*)d_ws;                    // q,k,v bf16: 3 x 16.78 MB
    u16* w3    = in_c + 3 * SZ_IN;              // [3*DM, DM]
    u16* wo_c  = w3   + 3 * SZ_W;
    u16* q_ws  = wo_c + SZ_W;                   // [b,h,s,dk] (pre-scaled)
    u16* k_ws  = q_ws + SZ_IN;
    u16* vt_ws = k_ws + SZ_IN;                  // [b,h,dk,s]
    u16* ctx   = in_c;                          // alias (inputs dead after QKV gemm)

    cast_all<<<14336, cblk, 0, stream>>>(q, k, v, Wq, Wk, Wv, Wo, in_c, w3, wo_c);
    gemm_k<0><<<ggq, cblk, 0, stream>>>(in_c, in_c + SZ_IN, in_c + 2 * SZ_IN, w3,
                                        bq, bk, bv, q_ws, k_ws, vt_ws, nullptr, 0);
    attn3<<<dim3(BATCH * NH, SEQ / 128), cblk, 0, stream>>>(q_ws, k_ws, vt_ws, ctx);
    gemm_k<1><<<ggs, cblk, 0, stream>>>(ctx, ctx, ctx, wo_c,
                                        bo, bo, bo, nullptr, nullptr, nullptr,
                                        (float*)d_out, 0);
  } else {
    u16* in_c  = (u16*)d_ws;                    // single 16.78 MB cast buffer
    u16* w3    = in_c + SZ_IN;
    u16* wo_c  = w3   + 3 * SZ_W;
    u16* q_ws  = wo_c + SZ_W;
    u16* k_ws  = q_ws + SZ_IN;
    u16* vt_ws = k_ws + SZ_IN;
    u16* ctx   = in_c;

    const int NA8 = MTOT * DM / 8;
    cast_w<<<2048, cblk, 0, stream>>>(Wq, Wk, Wv, Wo, w3, wo_c);
    cast_bf16<<<NA8 / 256, cblk, 0, stream>>>(q, in_c, NA8);
    gemm_k<0><<<ggs, cblk, 0, stream>>>(in_c, in_c, in_c, w3, bq, bk, bv,
                                        q_ws, k_ws, vt_ws, nullptr, 0);
    cast_bf16<<<NA8 / 256, cblk, 0, stream>>>(k, in_c, NA8);
    gemm_k<0><<<ggs, cblk, 0, stream>>>(in_c, in_c, in_c, w3, bq, bk, bv,
                                        q_ws, k_ws, vt_ws, nullptr, 1);
    cast_bf16<<<NA8 / 256, cblk, 0, stream>>>(v, in_c, NA8);
    gemm_k<0><<<ggs, cblk, 0, stream>>>(in_c, in_c, in_c, w3, bq, bk, bv,
                                        q_ws, k_ws, vt_ws, nullptr, 2);
    attn3<<<dim3(BATCH * NH, SEQ / 128), cblk, 0, stream>>>(q_ws, k_ws, vt_ws, ctx);
    gemm_k<1><<<ggs, cblk, 0, stream>>>(ctx, ctx, ctx, wo_c,
                                        bo, bo, bo, nullptr, nullptr, nullptr,
                                        (float*)d_out, 0);
  }
}